// Round 1
// baseline (604.073 us; speedup 1.0000x reference)
//
#include <hip/hip_runtime.h>
#include <stdint.h>

// GEMM: C[M,N] = X[M,K] * W[N,K]^T + bias, group-dequantized W (group=64 along K).
// Strategy: convert X->bf16 and dequant W->bf16 into d_ws, then m97-style
// bf16 MFMA GEMM (128x128 tile, BK=64, global_load_lds width=16, XOR-swizzled
// LDS to keep both async staging and ds_read_b128 conflict-free).

#define BM 128
#define BN 128
#define BK 64

typedef __attribute__((ext_vector_type(8))) short short8;     // 8 bf16 = 4 VGPRs
typedef __attribute__((ext_vector_type(8))) unsigned short ushort8;
typedef __attribute__((ext_vector_type(4))) float f32x4;
typedef __attribute__((ext_vector_type(4))) float float4v;
typedef __attribute__((ext_vector_type(4))) int int4v;

typedef __attribute__((address_space(1))) void g_void;
typedef __attribute__((address_space(3))) void l_void;

__device__ __forceinline__ unsigned short f2bf(float f) {
  union { float f; unsigned int u; } v; v.f = f;
  unsigned int r = v.u + 0x7FFFu + ((v.u >> 16) & 1u);  // round-to-nearest-even
  return (unsigned short)(r >> 16);
}

__device__ __forceinline__ void async_copy16(const void* g, void* l) {
  __builtin_amdgcn_global_load_lds((const g_void*)g, (l_void*)l, 16, 0, 0);
}

// ---- x: fp32 -> bf16, 8 elems/thread -------------------------------------
__global__ __launch_bounds__(256) void cvt_x_kernel(
    const float* __restrict__ x, unsigned short* __restrict__ o, int n8) {
  int t = blockIdx.x * 256 + threadIdx.x;
  if (t >= n8) return;
  const float4v* xp = (const float4v*)x + (size_t)t * 2;
  float4v a = xp[0], b = xp[1];
  ushort8 r;
  r[0] = f2bf(a[0]); r[1] = f2bf(a[1]); r[2] = f2bf(a[2]); r[3] = f2bf(a[3]);
  r[4] = f2bf(b[0]); r[5] = f2bf(b[1]); r[6] = f2bf(b[2]); r[7] = f2bf(b[3]);
  *(ushort8*)(o + (size_t)t * 8) = r;
}

// ---- W: int32 * group-scale -> bf16, 8 elems/thread (group=64 => t>>3) ---
__global__ __launch_bounds__(256) void cvt_w_kernel(
    const int* __restrict__ w, const float* __restrict__ s,
    unsigned short* __restrict__ o, int n8) {
  int t = blockIdx.x * 256 + threadIdx.x;
  if (t >= n8) return;
  const int4v* wp = (const int4v*)w + (size_t)t * 2;
  int4v q0 = wp[0], q1 = wp[1];
  float sc = s[t >> 3];
  ushort8 r;
  r[0] = f2bf((float)q0[0] * sc); r[1] = f2bf((float)q0[1] * sc);
  r[2] = f2bf((float)q0[2] * sc); r[3] = f2bf((float)q0[3] * sc);
  r[4] = f2bf((float)q1[0] * sc); r[5] = f2bf((float)q1[1] * sc);
  r[6] = f2bf((float)q1[2] * sc); r[7] = f2bf((float)q1[3] * sc);
  *(ushort8*)(o + (size_t)t * 8) = r;
}

// ---- GEMM ----------------------------------------------------------------
// LDS layout: A tile [128 rows][64 k] bf16 (128 B rows), B tile same at +16KB.
// Swizzle: slot [row][chunk c] holds global k-chunk (c ^ (row&7)); chunk = 8 bf16
// = 16 B. Staging matches global_load_lds's lane-ordered layout; compute reads
// ds_read_b128 land conflict-free (8 distinct chunks across lanes 0..7).
template <bool PRE>
__global__ __launch_bounds__(256) void gemm_kernel(
    const unsigned short* __restrict__ Xb,  // PRE: bf16 [M][K]
    const unsigned short* __restrict__ Wb,  // PRE: bf16 [N][K]
    const float* __restrict__ Xf,           // !PRE: fp32 x
    const int* __restrict__ Wq,             // !PRE: int32 W
    const float* __restrict__ Ws,           // !PRE: group scales
    const float* __restrict__ bias,
    float* __restrict__ C, int M, int N, int K) {
  __shared__ unsigned char smem[(BM * BK + BN * BK) * 2];  // 32 KB
  const int tid = threadIdx.x;
  const int lane = tid & 63, wid = tid >> 6;
  const int m0 = blockIdx.y * BM, n0 = blockIdx.x * BN;

  // staging geometry: per wave 32 rows (4 instrs x 8 rows), lane -> (row, chunk)
  const int sr = lane >> 3;             // sub-row 0..7
  const int fc = (lane & 7) ^ sr;       // swizzled chunk to fetch
  const int arow = m0 + wid * 32 + sr;  // + t*8
  const int brow = n0 + wid * 32 + sr;

  unsigned char* As = smem;
  unsigned char* Bs = smem + BM * BK * 2;
  unsigned char* ldsA = As + wid * 4096;  // wave-uniform base; HW adds lane*16
  unsigned char* ldsB = Bs + wid * 4096;
  unsigned char* stA = As + wid * 4096 + lane * 16;  // explicit writes (!PRE)
  unsigned char* stB = Bs + wid * 4096 + lane * 16;

  // compute-read geometry
  const int lm = lane & 15, lq = lane >> 4, le = lane & 7;
  const int wm = (wid & 1) * 64, wn = (wid >> 1) * 64;
  const int c0 = ((lq ^ le) << 4);        // ks=0 chunk byte offset
  const int c1 = (((lq + 4) ^ le) << 4);  // ks=1

  const int Kg = K >> 6;  // scale groups per W row

  f32x4 acc[4][4];
#pragma unroll
  for (int i = 0; i < 4; i++)
#pragma unroll
    for (int j = 0; j < 4; j++) acc[i][j] = (f32x4)(0.f);

  for (int k0 = 0; k0 < K; k0 += BK) {
    if (PRE) {
#pragma unroll
      for (int t = 0; t < 4; t++) {
        const unsigned short* ga = Xb + (size_t)(arow + t * 8) * K + k0 + fc * 8;
        async_copy16(ga, ldsA + t * 1024);
        const unsigned short* gb = Wb + (size_t)(brow + t * 8) * K + k0 + fc * 8;
        async_copy16(gb, ldsB + t * 1024);
      }
    } else {
#pragma unroll
      for (int t = 0; t < 4; t++) {
        const float4v* xa = (const float4v*)(Xf + (size_t)(arow + t * 8) * K + k0 + fc * 8);
        float4v x0 = xa[0], x1 = xa[1];
        ushort8 ra;
        ra[0] = f2bf(x0[0]); ra[1] = f2bf(x0[1]); ra[2] = f2bf(x0[2]); ra[3] = f2bf(x0[3]);
        ra[4] = f2bf(x1[0]); ra[5] = f2bf(x1[1]); ra[6] = f2bf(x1[2]); ra[7] = f2bf(x1[3]);
        *(ushort8*)(stA + t * 1024) = ra;

        const int4v* wq = (const int4v*)(Wq + (size_t)(brow + t * 8) * K + k0 + fc * 8);
        int4v q0 = wq[0], q1 = wq[1];
        float sc = Ws[(size_t)(brow + t * 8) * Kg + (k0 >> 6)];
        ushort8 rb;
        rb[0] = f2bf((float)q0[0] * sc); rb[1] = f2bf((float)q0[1] * sc);
        rb[2] = f2bf((float)q0[2] * sc); rb[3] = f2bf((float)q0[3] * sc);
        rb[4] = f2bf((float)q1[0] * sc); rb[5] = f2bf((float)q1[1] * sc);
        rb[6] = f2bf((float)q1[2] * sc); rb[7] = f2bf((float)q1[3] * sc);
        *(ushort8*)(stB + t * 1024) = rb;
      }
    }
    __syncthreads();

#pragma unroll
    for (int ks = 0; ks < 2; ks++) {
      const int co = ks ? c1 : c0;
      short8 ar[4], br[4];
#pragma unroll
      for (int i = 0; i < 4; i++) {
        ar[i] = *(const short8*)(As + (wm + i * 16 + lm) * 128 + co);
        br[i] = *(const short8*)(Bs + (wn + i * 16 + lm) * 128 + co);
      }
#pragma unroll
      for (int i = 0; i < 4; i++)
#pragma unroll
        for (int j = 0; j < 4; j++)
          acc[i][j] = __builtin_amdgcn_mfma_f32_16x16x32_bf16(ar[i], br[j], acc[i][j], 0, 0, 0);
    }
    __syncthreads();
  }

  // epilogue: C/D layout col = lane&15, row = (lane>>4)*4 + reg  [m89-verified]
  const int gm = m0 + wm, gn = n0 + wn;
#pragma unroll
  for (int j = 0; j < 4; j++) {
    const int col = gn + j * 16 + lm;
    const float bv = bias[col];
#pragma unroll
    for (int i = 0; i < 4; i++) {
      const int row0 = gm + i * 16 + lq * 4;
      f32x4 v = acc[i][j];
#pragma unroll
      for (int r = 0; r < 4; r++)
        C[(size_t)(row0 + r) * N + col] = v[r] + bv;
    }
  }
}

extern "C" void kernel_launch(void* const* d_in, const int* in_sizes, int n_in,
                              void* d_out, int out_size, void* d_ws, size_t ws_size,
                              hipStream_t stream) {
  const float* x = (const float*)d_in[0];
  const int* wq = (const int*)d_in[1];
  const float* wsc = (const float*)d_in[2];
  const float* bias = (const float*)d_in[3];
  float* out = (float*)d_out;

  const int N = in_sizes[3];            // D_out (bias length)
  const int K = in_sizes[1] / N;        // D_in
  const int M = in_sizes[0] / K;        // B*S

  const size_t needX = (size_t)M * K * 2;
  const size_t needW = (size_t)N * K * 2;
  dim3 grid(N / BN, M / BM), block(256);

  if (ws_size >= needX + needW) {
    unsigned short* Xb = (unsigned short*)d_ws;
    unsigned short* Wb = (unsigned short*)((char*)d_ws + needX);
    const int n8x = (M * K) / 8;
    cvt_x_kernel<<<(n8x + 255) / 256, 256, 0, stream>>>(x, Xb, n8x);
    const int n8w = (N * K) / 8;
    cvt_w_kernel<<<(n8w + 255) / 256, 256, 0, stream>>>(wq, wsc, Wb, n8w);
    gemm_kernel<true><<<grid, block, 0, stream>>>(Xb, Wb, nullptr, nullptr, nullptr,
                                                  bias, out, M, N, K);
  } else {
    gemm_kernel<false><<<grid, block, 0, stream>>>(nullptr, nullptr, x, wq, wsc,
                                                   bias, out, M, N, K);
  }
}

// Round 3
// 582.193 us; speedup vs baseline: 1.0376x; 1.0376x over previous
//
#include <hip/hip_runtime.h>
#include <stdint.h>

// GEMM: C[M,N] = X[M,K] * W[N,K]^T + bias, group-dequantized W (group=64 along K).
// R3: fix R2's LDS tile-stride bug (second m/n tile is +32 rows = +4096 B, not
// +8192 B which read past the 32KB shared alloc -> NaN). Core: 32x32x16 bf16
// MFMA, 128x128 tile, XOR-swizzled LDS, global_load_lds width=16 staging.

#define BM 128
#define BN 128
#define BK 64

typedef __attribute__((ext_vector_type(8))) short short8;       // 8 bf16 = 4 VGPRs
typedef __attribute__((ext_vector_type(8))) unsigned short ushort8;
typedef __attribute__((ext_vector_type(16))) float f32x16;
typedef __attribute__((ext_vector_type(4))) float float4v;
typedef __attribute__((ext_vector_type(4))) int int4v;

typedef __attribute__((address_space(1))) void g_void;
typedef __attribute__((address_space(3))) void l_void;

__device__ __forceinline__ unsigned short f2bf(float f) {
  union { float f; unsigned int u; } v; v.f = f;
  unsigned int r = v.u + 0x7FFFu + ((v.u >> 16) & 1u);  // round-to-nearest-even
  return (unsigned short)(r >> 16);
}

__device__ __forceinline__ void async_copy16(const void* g, void* l) {
  __builtin_amdgcn_global_load_lds((const g_void*)g, (l_void*)l, 16, 0, 0);
}

// ---- fused conversion: X fp32->bf16 and W int32*scale->bf16, 8 elem/thread ----
__global__ __launch_bounds__(256) void cvt_kernel(
    const float* __restrict__ x, const int* __restrict__ w,
    const float* __restrict__ s, unsigned short* __restrict__ ox,
    unsigned short* __restrict__ ow, int n8x, int n8w, int gx) {
  if ((int)blockIdx.x < gx) {
    int t = blockIdx.x * 256 + threadIdx.x;
    if (t >= n8x) return;
    const float4v* xp = (const float4v*)x + (size_t)t * 2;
    float4v a = xp[0], b = xp[1];
    ushort8 r;
    r[0] = f2bf(a[0]); r[1] = f2bf(a[1]); r[2] = f2bf(a[2]); r[3] = f2bf(a[3]);
    r[4] = f2bf(b[0]); r[5] = f2bf(b[1]); r[6] = f2bf(b[2]); r[7] = f2bf(b[3]);
    *(ushort8*)(ox + (size_t)t * 8) = r;
  } else {
    int t = ((int)blockIdx.x - gx) * 256 + threadIdx.x;
    if (t >= n8w) return;
    const int4v* wp = (const int4v*)w + (size_t)t * 2;
    int4v q0 = wp[0], q1 = wp[1];
    float sc = s[t >> 3];  // GROUP_SIZE=64 = 8 threads x 8 elems
    ushort8 r;
    r[0] = f2bf((float)q0[0] * sc); r[1] = f2bf((float)q0[1] * sc);
    r[2] = f2bf((float)q0[2] * sc); r[3] = f2bf((float)q0[3] * sc);
    r[4] = f2bf((float)q1[0] * sc); r[5] = f2bf((float)q1[1] * sc);
    r[6] = f2bf((float)q1[2] * sc); r[7] = f2bf((float)q1[3] * sc);
    *(ushort8*)(ow + (size_t)t * 8) = r;
  }
}

// ---- GEMM ----------------------------------------------------------------
// LDS: A tile [128 rows][64 k] bf16 (128 B rows), B tile same at +16KB.
// Slot [row][c] holds global k-chunk (c ^ (row&7)); chunk = 8 bf16 = 16 B.
// Staging matches global_load_lds lane order; ds_read_b128 conflict-free.
// Compute: 4 waves x (2x2 tiles of v_mfma_f32_32x32x16_bf16), BK/16=4 k-steps.
// Each wave: 64x64 output; m-tiles at rows wm+{0,32}, n-tiles at cols wn+{0,32}.
template <bool PRE>
__global__ __launch_bounds__(256) void gemm_kernel(
    const unsigned short* __restrict__ Xb,  // PRE: bf16 [M][K]
    const unsigned short* __restrict__ Wb,  // PRE: bf16 [N][K]
    const float* __restrict__ Xf,           // !PRE: fp32 x
    const int* __restrict__ Wq,             // !PRE: int32 W
    const float* __restrict__ Ws,           // !PRE: group scales
    const float* __restrict__ bias,
    float* __restrict__ C, int M, int N, int K) {
  __shared__ unsigned char smem[(BM * BK + BN * BK) * 2];  // 32 KB
  const int tid = threadIdx.x;
  const int lane = tid & 63, wid = tid >> 6;
  const int m0 = blockIdx.y * BM, n0 = blockIdx.x * BN;

  // staging: per wave 32 rows (4 instrs x 8 rows); lane -> (sub-row, chunk)
  const int sr = lane >> 3;             // 0..7
  const int fc = (lane & 7) ^ sr;       // swizzled chunk to fetch
  const int arow = m0 + wid * 32 + sr;  // + t*8
  const int brow = n0 + wid * 32 + sr;

  unsigned char* As = smem;
  unsigned char* Bs = smem + BM * BK * 2;
  unsigned char* ldsA = As + wid * 4096;  // wave-uniform base; HW adds lane*16
  unsigned char* ldsB = Bs + wid * 4096;
  unsigned char* stA = As + wid * 4096 + lane * 16;  // explicit writes (!PRE)
  unsigned char* stB = Bs + wid * 4096 + lane * 16;

  // compute-read geometry (32x32x16: A[m=lane&31][k=(lane>>5)*8+j])
  const int l31 = lane & 31, lh = lane >> 5, le = lane & 7;
  const int wm = (wid & 1) * 64, wn = (wid >> 1) * 64;
  const int aB0 = (wm + l31) * 128, bB0 = (wn + l31) * 128;

  const int Kg = K >> 6;

  f32x16 acc[2][2];
#pragma unroll
  for (int i = 0; i < 2; i++)
#pragma unroll
    for (int j = 0; j < 2; j++) acc[i][j] = (f32x16)(0.f);

  for (int k0 = 0; k0 < K; k0 += BK) {
    if (PRE) {
#pragma unroll
      for (int t = 0; t < 4; t++) {
        const unsigned short* ga = Xb + (size_t)(arow + t * 8) * K + k0 + fc * 8;
        async_copy16(ga, ldsA + t * 1024);
        const unsigned short* gb = Wb + (size_t)(brow + t * 8) * K + k0 + fc * 8;
        async_copy16(gb, ldsB + t * 1024);
      }
    } else {
#pragma unroll
      for (int t = 0; t < 4; t++) {
        const float4v* xa = (const float4v*)(Xf + (size_t)(arow + t * 8) * K + k0 + fc * 8);
        float4v x0 = xa[0], x1 = xa[1];
        ushort8 ra;
        ra[0] = f2bf(x0[0]); ra[1] = f2bf(x0[1]); ra[2] = f2bf(x0[2]); ra[3] = f2bf(x0[3]);
        ra[4] = f2bf(x1[0]); ra[5] = f2bf(x1[1]); ra[6] = f2bf(x1[2]); ra[7] = f2bf(x1[3]);
        *(ushort8*)(stA + t * 1024) = ra;

        const int4v* wq = (const int4v*)(Wq + (size_t)(brow + t * 8) * K + k0 + fc * 8);
        int4v q0 = wq[0], q1 = wq[1];
        float sc = Ws[(size_t)(brow + t * 8) * Kg + (k0 >> 6)];
        ushort8 rb;
        rb[0] = f2bf((float)q0[0] * sc); rb[1] = f2bf((float)q0[1] * sc);
        rb[2] = f2bf((float)q0[2] * sc); rb[3] = f2bf((float)q0[3] * sc);
        rb[4] = f2bf((float)q1[0] * sc); rb[5] = f2bf((float)q1[1] * sc);
        rb[6] = f2bf((float)q1[2] * sc); rb[7] = f2bf((float)q1[3] * sc);
        *(ushort8*)(stB + t * 1024) = rb;
      }
    }
    __syncthreads();

#pragma unroll
    for (int s = 0; s < 4; s++) {
      const int off = ((2 * s + lh) ^ le) << 4;  // chunk cc = 2s+lh, swizzled
      short8 a0 = *(const short8*)(As + aB0 + off);
      short8 a1 = *(const short8*)(As + aB0 + 4096 + off);   // +32 rows
      short8 b0 = *(const short8*)(Bs + bB0 + off);
      short8 b1 = *(const short8*)(Bs + bB0 + 4096 + off);   // +32 rows
      acc[0][0] = __builtin_amdgcn_mfma_f32_32x32x16_bf16(a0, b0, acc[0][0], 0, 0, 0);
      acc[0][1] = __builtin_amdgcn_mfma_f32_32x32x16_bf16(a0, b1, acc[0][1], 0, 0, 0);
      acc[1][0] = __builtin_amdgcn_mfma_f32_32x32x16_bf16(a1, b0, acc[1][0], 0, 0, 0);
      acc[1][1] = __builtin_amdgcn_mfma_f32_32x32x16_bf16(a1, b1, acc[1][1], 0, 0, 0);
    }
    __syncthreads();
  }

  // epilogue: C/D 32x32 layout col=lane&31, row=(reg&3)+8*(reg>>2)+4*(lane>>5)
  const int gm = m0 + wm + 4 * lh, gn = n0 + wn + l31;
#pragma unroll
  for (int j = 0; j < 2; j++) {
    const int col = gn + j * 32;
    const float bv = bias[col];
#pragma unroll
    for (int i = 0; i < 2; i++) {
      const int rbase = gm + i * 32;  // second m-tile is +32 rows
      f32x16 v = acc[i][j];
#pragma unroll
      for (int r = 0; r < 16; r++) {
        const int row = rbase + (r & 3) + 8 * (r >> 2);
        C[(size_t)row * N + col] = v[r] + bv;
      }
    }
  }
}

extern "C" void kernel_launch(void* const* d_in, const int* in_sizes, int n_in,
                              void* d_out, int out_size, void* d_ws, size_t ws_size,
                              hipStream_t stream) {
  const float* x = (const float*)d_in[0];
  const int* wq = (const int*)d_in[1];
  const float* wsc = (const float*)d_in[2];
  const float* bias = (const float*)d_in[3];
  float* out = (float*)d_out;

  const int N = in_sizes[3];            // D_out (bias length)
  const int K = in_sizes[1] / N;        // D_in
  const int M = in_sizes[0] / K;        // B*S

  const size_t needX = (size_t)M * K * 2;
  const size_t needW = (size_t)N * K * 2;
  dim3 grid(N / BN, M / BM), block(256);

  if (ws_size >= needX + needW) {
    unsigned short* Xb = (unsigned short*)d_ws;
    unsigned short* Wb = (unsigned short*)((char*)d_ws + needX);
    const int n8x = (M * K) / 8, n8w = (N * K) / 8;
    const int gx = (n8x + 255) / 256, gw = (n8w + 255) / 256;
    cvt_kernel<<<gx + gw, 256, 0, stream>>>(x, wq, wsc, Xb, Wb, n8x, n8w, gx);
    gemm_kernel<true><<<grid, block, 0, stream>>>(Xb, Wb, nullptr, nullptr, nullptr,
                                                  bias, out, M, N, K);
  } else {
    gemm_kernel<false><<<grid, block, 0, stream>>>(nullptr, nullptr, x, wq, wsc,
                                                   bias, out, M, N, K);
  }
}

// Round 4
// 539.982 us; speedup vs baseline: 1.1187x; 1.0782x over previous
//
#include <hip/hip_runtime.h>
#include <stdint.h>

// GEMM: C[M,N] = X[M,K] * W[N,K]^T + bias, group-dequantized W (group=64 along K).
// R4: occupancy push. __launch_bounds__(256,4) caps unified regs at 128
// (64 AGPR acc + <=48 arch VGPR) -> 4 blocks/CU (was ~2, Occupancy 22%).
// 32-bit staging offsets to fit the cap. MFMA step s consumes chunk pair
// (s, s+4) instead of (2s,2s+1) -- correctness-neutral K-permutation, probes
// the bank-conflict mechanism (R3: exactly 4 conflict-cyc/ds_read_b128).

#define BM 128
#define BN 128
#define BK 64

typedef __attribute__((ext_vector_type(8))) short short8;       // 8 bf16 = 4 VGPRs
typedef __attribute__((ext_vector_type(8))) unsigned short ushort8;
typedef __attribute__((ext_vector_type(16))) float f32x16;
typedef __attribute__((ext_vector_type(4))) float float4v;
typedef __attribute__((ext_vector_type(4))) int int4v;

typedef __attribute__((address_space(1))) void g_void;
typedef __attribute__((address_space(3))) void l_void;

__device__ __forceinline__ unsigned short f2bf(float f) {
  union { float f; unsigned int u; } v; v.f = f;
  unsigned int r = v.u + 0x7FFFu + ((v.u >> 16) & 1u);  // round-to-nearest-even
  return (unsigned short)(r >> 16);
}

__device__ __forceinline__ void async_copy16(const void* g, void* l) {
  __builtin_amdgcn_global_load_lds((const g_void*)g, (l_void*)l, 16, 0, 0);
}

// ---- fused conversion: X fp32->bf16 and W int32*scale->bf16, 8 elem/thread ----
__global__ __launch_bounds__(256) void cvt_kernel(
    const float* __restrict__ x, const int* __restrict__ w,
    const float* __restrict__ s, unsigned short* __restrict__ ox,
    unsigned short* __restrict__ ow, int n8x, int n8w, int gx) {
  if ((int)blockIdx.x < gx) {
    int t = blockIdx.x * 256 + threadIdx.x;
    if (t >= n8x) return;
    const float4v* xp = (const float4v*)x + (size_t)t * 2;
    float4v a = xp[0], b = xp[1];
    ushort8 r;
    r[0] = f2bf(a[0]); r[1] = f2bf(a[1]); r[2] = f2bf(a[2]); r[3] = f2bf(a[3]);
    r[4] = f2bf(b[0]); r[5] = f2bf(b[1]); r[6] = f2bf(b[2]); r[7] = f2bf(b[3]);
    *(ushort8*)(ox + (size_t)t * 8) = r;
  } else {
    int t = ((int)blockIdx.x - gx) * 256 + threadIdx.x;
    if (t >= n8w) return;
    const int4v* wp = (const int4v*)w + (size_t)t * 2;
    int4v q0 = wp[0], q1 = wp[1];
    float sc = s[t >> 3];  // GROUP_SIZE=64 = 8 threads x 8 elems
    ushort8 r;
    r[0] = f2bf((float)q0[0] * sc); r[1] = f2bf((float)q0[1] * sc);
    r[2] = f2bf((float)q0[2] * sc); r[3] = f2bf((float)q0[3] * sc);
    r[4] = f2bf((float)q1[0] * sc); r[5] = f2bf((float)q1[1] * sc);
    r[6] = f2bf((float)q1[2] * sc); r[7] = f2bf((float)q1[3] * sc);
    *(ushort8*)(ow + (size_t)t * 8) = r;
  }
}

// ---- main GEMM (pre-converted bf16 inputs) -------------------------------
// LDS: A tile [128 rows][64 k] bf16 (128 B rows), B at +16KB. Slot [row][c]
// holds global k-chunk (c ^ (row&7)); chunk = 8 bf16 = 16 B.
// 4 waves x (2x2 tiles of v_mfma_f32_32x32x16_bf16); wave tile 64x64.
__global__ __launch_bounds__(256, 4) void gemm_pre(
    const unsigned short* __restrict__ Xb,  // bf16 [M][K]
    const unsigned short* __restrict__ Wb,  // bf16 [N][K]
    const float* __restrict__ bias,
    float* __restrict__ C, int M, int N, int K) {
  __shared__ unsigned char smem[(BM * BK + BN * BK) * 2];  // 32 KB
  const int tid = threadIdx.x;
  const int lane = tid & 63, wid = tid >> 6;
  const int m0 = blockIdx.y * BM, n0 = blockIdx.x * BN;

  // staging: per wave 32 rows (4 instrs x 8 rows); lane -> (sub-row, chunk)
  const int sr = lane >> 3;             // 0..7
  const int fc = (lane & 7) ^ sr;       // swizzled chunk to fetch
  // 32-bit byte offsets (t=0, k=0); t-stride = K*16 B and k-advance are uniform
  const int offA = ((m0 + wid * 32 + sr) * K + fc * 8) * 2;
  const int offB = ((n0 + wid * 32 + sr) * K + fc * 8) * 2;
  const char* Xc = (const char*)Xb;
  const char* Wc = (const char*)Wb;

  unsigned char* As = smem;
  unsigned char* Bs = smem + BM * BK * 2;
  unsigned char* ldsA = As + wid * 4096;  // wave-uniform base; HW adds lane*16
  unsigned char* ldsB = Bs + wid * 4096;

  // compute-read geometry (32x32x16: A[m=lane&31][k=(lane>>5)*8+j])
  const int l31 = lane & 31, lh = lane >> 5, le = lane & 7;
  const int wm = (wid & 1) * 64, wn = (wid >> 1) * 64;
  const unsigned char* Aw = As + (wm + l31) * 128;
  const unsigned char* Bw = Bs + (wn + l31) * 128;

  f32x16 acc[2][2];
#pragma unroll
  for (int i = 0; i < 2; i++)
#pragma unroll
    for (int j = 0; j < 2; j++) acc[i][j] = (f32x16)(0.f);

  for (int k0 = 0; k0 < K; k0 += BK) {
    const int kb = k0 * 2;
#pragma unroll
    for (int t = 0; t < 4; t++) {
      async_copy16(Xc + (size_t)(offA + kb) + (size_t)t * (K * 16), ldsA + t * 1024);
      async_copy16(Wc + (size_t)(offB + kb) + (size_t)t * (K * 16), ldsB + t * 1024);
    }
    __syncthreads();

#pragma unroll
    for (int s = 0; s < 4; s++) {
      // MFMA step s consumes global chunks {s (half 0), s+4 (half 1)}:
      // K-permutation applied identically to A and B -> dot unchanged.
      const int off = ((s + 4 * lh) ^ le) << 4;
      short8 a0 = *(const short8*)(Aw + off);
      short8 a1 = *(const short8*)(Aw + 4096 + off);   // +32 rows
      short8 b0 = *(const short8*)(Bw + off);
      short8 b1 = *(const short8*)(Bw + 4096 + off);
      acc[0][0] = __builtin_amdgcn_mfma_f32_32x32x16_bf16(a0, b0, acc[0][0], 0, 0, 0);
      acc[0][1] = __builtin_amdgcn_mfma_f32_32x32x16_bf16(a0, b1, acc[0][1], 0, 0, 0);
      acc[1][0] = __builtin_amdgcn_mfma_f32_32x32x16_bf16(a1, b0, acc[1][0], 0, 0, 0);
      acc[1][1] = __builtin_amdgcn_mfma_f32_32x32x16_bf16(a1, b1, acc[1][1], 0, 0, 0);
    }
    __syncthreads();
  }

  // epilogue: C/D 32x32 layout col=lane&31, row=(reg&3)+8*(reg>>2)+4*(lane>>5)
  const int gm = m0 + wm + 4 * lh, gn = n0 + wn + l31;
#pragma unroll
  for (int j = 0; j < 2; j++) {
    const int col = gn + j * 32;
    const float bv = bias[col];
#pragma unroll
    for (int i = 0; i < 2; i++) {
      const int rbase = gm + i * 32;  // second m-tile is +32 rows
      f32x16 v = acc[i][j];
#pragma unroll
      for (int r = 0; r < 16; r++) {
        const int row = rbase + (r & 3) + 8 * (r >> 2);
        C[(size_t)row * N + col] = v[r] + bv;
      }
    }
  }
}

// ---- fallback: fused dequant GEMM (only if ws too small; never bounded) --
__global__ __launch_bounds__(256) void gemm_fused(
    const float* __restrict__ Xf, const int* __restrict__ Wq,
    const float* __restrict__ Ws, const float* __restrict__ bias,
    float* __restrict__ C, int M, int N, int K) {
  __shared__ unsigned char smem[(BM * BK + BN * BK) * 2];
  const int tid = threadIdx.x;
  const int lane = tid & 63, wid = tid >> 6;
  const int m0 = blockIdx.y * BM, n0 = blockIdx.x * BN;
  const int sr = lane >> 3, fc = (lane & 7) ^ sr;
  const int arow = m0 + wid * 32 + sr, brow = n0 + wid * 32 + sr;
  unsigned char* As = smem;
  unsigned char* Bs = smem + BM * BK * 2;
  unsigned char* stA = As + wid * 4096 + lane * 16;
  unsigned char* stB = Bs + wid * 4096 + lane * 16;
  const int l31 = lane & 31, lh = lane >> 5, le = lane & 7;
  const int wm = (wid & 1) * 64, wn = (wid >> 1) * 64;
  const unsigned char* Aw = As + (wm + l31) * 128;
  const unsigned char* Bw = Bs + (wn + l31) * 128;
  const int Kg = K >> 6;

  f32x16 acc[2][2];
#pragma unroll
  for (int i = 0; i < 2; i++)
#pragma unroll
    for (int j = 0; j < 2; j++) acc[i][j] = (f32x16)(0.f);

  for (int k0 = 0; k0 < K; k0 += BK) {
#pragma unroll
    for (int t = 0; t < 4; t++) {
      const float4v* xa = (const float4v*)(Xf + (size_t)(arow + t * 8) * K + k0 + fc * 8);
      float4v x0 = xa[0], x1 = xa[1];
      ushort8 ra;
      ra[0] = f2bf(x0[0]); ra[1] = f2bf(x0[1]); ra[2] = f2bf(x0[2]); ra[3] = f2bf(x0[3]);
      ra[4] = f2bf(x1[0]); ra[5] = f2bf(x1[1]); ra[6] = f2bf(x1[2]); ra[7] = f2bf(x1[3]);
      *(ushort8*)(stA + t * 1024) = ra;
      const int4v* wq = (const int4v*)(Wq + (size_t)(brow + t * 8) * K + k0 + fc * 8);
      int4v q0 = wq[0], q1 = wq[1];
      float sc = Ws[(size_t)(brow + t * 8) * Kg + (k0 >> 6)];
      ushort8 rb;
      rb[0] = f2bf((float)q0[0] * sc); rb[1] = f2bf((float)q0[1] * sc);
      rb[2] = f2bf((float)q0[2] * sc); rb[3] = f2bf((float)q0[3] * sc);
      rb[4] = f2bf((float)q1[0] * sc); rb[5] = f2bf((float)q1[1] * sc);
      rb[6] = f2bf((float)q1[2] * sc); rb[7] = f2bf((float)q1[3] * sc);
      *(ushort8*)(stB + t * 1024) = rb;
    }
    __syncthreads();
#pragma unroll
    for (int s = 0; s < 4; s++) {
      const int off = ((s + 4 * lh) ^ le) << 4;
      short8 a0 = *(const short8*)(Aw + off);
      short8 a1 = *(const short8*)(Aw + 4096 + off);
      short8 b0 = *(const short8*)(Bw + off);
      short8 b1 = *(const short8*)(Bw + 4096 + off);
      acc[0][0] = __builtin_amdgcn_mfma_f32_32x32x16_bf16(a0, b0, acc[0][0], 0, 0, 0);
      acc[0][1] = __builtin_amdgcn_mfma_f32_32x32x16_bf16(a0, b1, acc[0][1], 0, 0, 0);
      acc[1][0] = __builtin_amdgcn_mfma_f32_32x32x16_bf16(a1, b0, acc[1][0], 0, 0, 0);
      acc[1][1] = __builtin_amdgcn_mfma_f32_32x32x16_bf16(a1, b1, acc[1][1], 0, 0, 0);
    }
    __syncthreads();
  }

  const int gm = m0 + wm + 4 * lh, gn = n0 + wn + l31;
#pragma unroll
  for (int j = 0; j < 2; j++) {
    const int col = gn + j * 32;
    const float bv = bias[col];
#pragma unroll
    for (int i = 0; i < 2; i++) {
      const int rbase = gm + i * 32;
      f32x16 v = acc[i][j];
#pragma unroll
      for (int r = 0; r < 16; r++) {
        const int row = rbase + (r & 3) + 8 * (r >> 2);
        C[(size_t)row * N + col] = v[r] + bv;
      }
    }
  }
}

extern "C" void kernel_launch(void* const* d_in, const int* in_sizes, int n_in,
                              void* d_out, int out_size, void* d_ws, size_t ws_size,
                              hipStream_t stream) {
  const float* x = (const float*)d_in[0];
  const int* wq = (const int*)d_in[1];
  const float* wsc = (const float*)d_in[2];
  const float* bias = (const float*)d_in[3];
  float* out = (float*)d_out;

  const int N = in_sizes[3];            // D_out (bias length)
  const int K = in_sizes[1] / N;        // D_in
  const int M = in_sizes[0] / K;        // B*S

  const size_t needX = (size_t)M * K * 2;
  const size_t needW = (size_t)N * K * 2;
  dim3 grid(N / BN, M / BM), block(256);

  if (ws_size >= needX + needW) {
    unsigned short* Xb = (unsigned short*)d_ws;
    unsigned short* Wb = (unsigned short*)((char*)d_ws + needX);
    const int n8x = (M * K) / 8, n8w = (N * K) / 8;
    const int gx = (n8x + 255) / 256, gw = (n8w + 255) / 256;
    cvt_kernel<<<gx + gw, 256, 0, stream>>>(x, wq, wsc, Xb, Wb, n8x, n8w, gx);
    gemm_pre<<<grid, block, 0, stream>>>(Xb, Wb, bias, out, M, N, K);
  } else {
    gemm_fused<<<grid, block, 0, stream>>>(x, wq, wsc, bias, out, M, N, K);
  }
}